// Round 8
// baseline (220.414 us; speedup 1.0000x reference)
//
#include <hip/hip_runtime.h>

// SimpleMatcher: B=128, N=900 preds, T=300 targets.
// out = [pred_idx (B*T), valid (B*T), max_iou (B*T)] as float.
//
// R8: single fused kernel.
//  - LDS-free hot loop: pred box loaded via readfirstlane-uniform index
//    (scalar-promotable), converted cxcywh->xyxy in-loop (9 VALU per k,
//    amortized over 300 pairs). No staging, no mid-loop syncthreads.
//  - 5 targets/lane (60 lanes x 5 = 300), 5 independent dep chains.
//  - Decoupled completion: each (b,ns) block writes slice top-2 partials,
//    __threadfence + atomicAdd(done[b]); the LAST block for b performs the
//    final reduce + margin test + bit-exact winner recompute + exact rescan
//    of ambiguous targets. One kernel node + one 512B memset node.
// Numerics: approx g = (inter*ea + uni*(uni-ea)) * rcp(uni*ea); |err| vs
// reference <= ~1e-6. MARGIN 2e-5 > 2*err -> approx argmax provably equals
// exact argmax when best-second > MARGIN; winner's GIoU recomputed with
// IEEE ops in numpy's exact expression order; ambiguous targets (rare)
// exhaustively rescanned exactly with first-occurrence tie-break.

#define BB 128
#define NN 900
#define TT 300
#define NSPLIT 9       // blocks per batch; last one finishes
#define NPB 100        // preds per block  (NN / NSPLIT)
#define NPW 25         // preds per wave   (NPB / 4)
#define TPL 5          // targets per lane
#define ALANES 60      // active lanes (60*5 = 300)
#define MARGIN 2e-5f

// Bit-exact GIoU in numpy's exact expression order.
__device__ __forceinline__ float giou_exact(float4 pb, float4 tb) {
#pragma clang fp contract(off)
    float px0 = pb.x - 0.5f * pb.z, py0 = pb.y - 0.5f * pb.w;
    float px1 = pb.x + 0.5f * pb.z, py1 = pb.y + 0.5f * pb.w;
    float tx0 = tb.x - 0.5f * tb.z, ty0 = tb.y - 0.5f * tb.w;
    float tx1 = tb.x + 0.5f * tb.z, ty1 = tb.y + 0.5f * tb.w;
    float pa = (px1 - px0) * (py1 - py0);
    float ta = (tx1 - tx0) * (ty1 - ty0);
    float w  = fmaxf(fminf(px1, tx1) - fmaxf(px0, tx0), 0.f);
    float h  = fmaxf(fminf(py1, ty1) - fmaxf(py0, ty0), 0.f);
    float inter = w * h;
    float uni   = pa + ta - inter;
    float iou   = inter / uni;            // correctly-rounded IEEE div
    float ew = fmaxf(fmaxf(px1, tx1) - fminf(px0, tx0), 0.f);
    float eh = fmaxf(fmaxf(py1, ty1) - fminf(py0, ty0), 0.f);
    float ea = ew * eh;
    return iou - (ea - uni) / ea;         // correctly-rounded IEEE div
}

__global__ __launch_bounds__(256) void matcher_kernel(
    const float* __restrict__ pred,          // [B,N,4] cxcywh
    const float* __restrict__ tgt,           // [B,T,4] cxcywh
    const unsigned char* __restrict__ mask,  // [B,T] bool
    float* __restrict__ pbest,               // [NSPLIT][B*T]
    float* __restrict__ psec,                // [NSPLIT][B*T]
    int*   __restrict__ pidx,                // [NSPLIT][B*T]
    unsigned int* __restrict__ done,         // [B], pre-zeroed
    float* __restrict__ out)                 // [3, B*T]
{
    __shared__ float sbv[4 * TT], ssv[4 * TT];
    __shared__ int   siv[4 * TT];
    __shared__ int   slast;
    __shared__ int   sflag[TT + 4];
    __shared__ int   scount;

    const int ns  = blockIdx.x % NSPLIT;
    const int b   = blockIdx.x / NSPLIT;
    const int tid = threadIdx.x;
    const int l   = tid & 63;
    const int ng  = tid >> 6;

    // ---- 5 target boxes per lane (lanes 0..59), exact reference order ----
    float tx0[TPL], ty0[TPL], tx1[TPL], ty1[TPL], ta[TPL];
    #pragma unroll
    for (int j = 0; j < TPL; ++j) {
        tx0[j] = ty0[j] = tx1[j] = ty1[j] = ta[j] = 0.f;
        if (l < ALANES) {
            const float4 tb = ((const float4*)tgt)[b * TT + j * ALANES + l];
            tx0[j] = tb.x - 0.5f * tb.z;
            ty0[j] = tb.y - 0.5f * tb.w;
            tx1[j] = tb.x + 0.5f * tb.z;
            ty1[j] = tb.y + 0.5f * tb.w;
            ta[j]  = (tx1[j] - tx0[j]) * (ty1[j] - ty0[j]);
        }
    }

    float best[TPL], sec[TPL];
    int   bl[TPL];
    #pragma unroll
    for (int j = 0; j < TPL; ++j) { best[j] = -INFINITY; sec[j] = -INFINITY; bl[j] = 0; }

    // wave-uniform base index -> scalar-promotable pred loads, no LDS
    const int base = __builtin_amdgcn_readfirstlane(b * NN + ns * NPB + ng * NPW);
    for (int k = 0; k < NPW; ++k) {
        const float4 p = ((const float4*)pred)[base + k];
        const float px0 = p.x - 0.5f * p.z;
        const float py0 = p.y - 0.5f * p.w;
        const float px1 = p.x + 0.5f * p.z;
        const float py1 = p.y + 0.5f * p.w;
        const float pa  = (px1 - px0) * (py1 - py0);
        #pragma unroll
        for (int j = 0; j < TPL; ++j) {
            const float w   = fmaxf(fminf(px1, tx1[j]) - fmaxf(px0, tx0[j]), 0.f);
            const float h   = fmaxf(fminf(py1, ty1[j]) - fmaxf(py0, ty0[j]), 0.f);
            const float inter = w * h;
            const float uni   = pa + ta[j] - inter;
            const float ew  = fmaxf(px1, tx1[j]) - fminf(px0, tx0[j]);  // >= 0
            const float eh  = fmaxf(py1, ty1[j]) - fminf(py0, ty0[j]);  // >= 0
            const float ea  = ew * eh;
            const float den = uni * ea;
            // g = inter/uni - (ea-uni)/ea = (inter*ea + uni*(uni-ea))/den
            const float num = fmaf(inter, ea, fmaf(uni, uni, -den));
            const float g   = num * __builtin_amdgcn_rcpf(den);

            sec[j] = __builtin_amdgcn_fmed3f(g, best[j], sec[j]);
            if (g > best[j]) bl[j] = k;
            best[j] = fmaxf(best[j], g);
        }
    }

    if (l < ALANES) {
        #pragma unroll
        for (int j = 0; j < TPL; ++j) {
            const int u = j * ALANES + l;
            sbv[ng * TT + u] = best[j];
            ssv[ng * TT + u] = sec[j];
            siv[ng * TT + u] = ng * NPW + bl[j];   // block-local pred index
        }
    }
    __syncthreads();

    // ---- cross-wave reduce (ascending wave = ascending n), write partials ----
    for (int u = tid; u < TT; u += 256) {
        float bb = -INFINITY, ss = -INFINITY;
        int   bi = 0;
        #pragma unroll
        for (int s = 0; s < 4; ++s) {
            const float ob = sbv[s * TT + u];
            const float os = ssv[s * TT + u];
            const int   oi = siv[s * TT + u];
            ss = fmaxf(fminf(bb, ob), fmaxf(ss, os));
            if (ob > bb) { bb = ob; bi = oi; }
        }
        const int bt = b * TT + u;
        pbest[ns * BB * TT + bt] = bb;
        psec [ns * BB * TT + bt] = ss;
        pidx [ns * BB * TT + bt] = ns * NPB + bi;   // global pred index
    }

    // ---- decoupled completion: last block for this b finishes ----
    __threadfence();                        // release partials device-wide
    if (tid == 0) {
        const unsigned int old = atomicAdd(&done[b], 1u);
        slast = (old == NSPLIT - 1) ? 1 : 0;
        scount = 0;
    }
    __syncthreads();
    if (!slast) return;
    __threadfence();                        // acquire partials

    for (int u = tid; u < TT; u += 256) {
        float bb = -INFINITY, ss = -INFINITY;
        int   bi = 0;
        #pragma unroll
        for (int s = 0; s < NSPLIT; ++s) {  // ascending ns = ascending n
            const float ob = pbest[s * BB * TT + b * TT + u];
            const float os = psec [s * BB * TT + b * TT + u];
            const int   oi = pidx [s * BB * TT + b * TT + u];
            ss = fmaxf(fminf(bb, ob), fmaxf(ss, os));
            if (ob > bb) { bb = ob; bi = oi; }
        }
        const int bt = b * TT + u;
        if (bb - ss > MARGIN) {
            // approx argmax provably exact; recompute winner bit-exactly
            const float4 pb = ((const float4*)pred)[b * NN + bi];
            const float4 tb = ((const float4*)tgt)[bt];
            const float g = giou_exact(pb, tb);
            const bool valid = (mask[bt] != 0) && (g >= 0.5f);
            out[bt]               = (float)bi;
            out[BB * TT + bt]     = valid ? 1.f : 0.f;
            out[2 * BB * TT + bt] = g;
        } else {
            const int pos = atomicAdd(&scount, 1);
            sflag[pos] = u;
        }
    }
    __syncthreads();

    // ---- exact rescan of ambiguous targets: one wave per entry ----
    const int cnt = scount;
    for (int f = ng; f < cnt; f += 4) {
        const int u   = sflag[f];
        const int fbt = b * TT + u;
        const float4 tb = ((const float4*)tgt)[fbt];

        float bestx = -INFINITY;
        int   bix   = NN;
        for (int n = l; n < NN; n += 64) {      // ascending n per lane
            const float4 pb = ((const float4*)pred)[b * NN + n];
            const float g = giou_exact(pb, tb);
            if (g > bestx) { bestx = g; bix = n; }
        }
        // cross-lane reduce: max g, lowest n on bit-ties (first occurrence)
        for (int off = 32; off >= 1; off >>= 1) {
            const float ob = __shfl_xor(bestx, off);
            const int   oi = __shfl_xor(bix, off);
            if (ob > bestx || (ob == bestx && oi < bix)) { bestx = ob; bix = oi; }
        }
        if (l == 0) {
            const bool valid = (mask[fbt] != 0) && (bestx >= 0.5f);
            out[fbt]               = (float)bix;
            out[BB * TT + fbt]     = valid ? 1.f : 0.f;
            out[2 * BB * TT + fbt] = bestx;
        }
    }
}

extern "C" void kernel_launch(void* const* d_in, const int* in_sizes, int n_in,
                              void* d_out, int out_size, void* d_ws, size_t ws_size,
                              hipStream_t stream) {
    const float* pred = (const float*)d_in[0];
    const float* tgt  = (const float*)d_in[1];
    const unsigned char* mask = (const unsigned char*)d_in[2];
    float* out = (float*)d_out;

    const size_t seg = (size_t)NSPLIT * BB * TT * 4;   // 1.38 MB per array
    char* ws = (char*)d_ws;
    float* pbest = (float*)ws;
    float* psec  = (float*)(ws + seg);
    int*   pidx  = (int*)  (ws + 2 * seg);
    unsigned int* done = (unsigned int*)(ws + 3 * seg); // [BB]

    hipMemsetAsync(done, 0, BB * sizeof(unsigned int), stream);
    matcher_kernel<<<dim3(BB * NSPLIT), dim3(256), 0, stream>>>(
        pred, tgt, mask, pbest, psec, pidx, done, out);
}

// Round 9
// 95.608 us; speedup vs baseline: 2.3054x; 2.3054x over previous
//
#include <hip/hip_runtime.h>

// SimpleMatcher: B=128, N=900 preds, T=300 targets.
// out = [pred_idx (B*T), valid (B*T), max_iou (B*T)] as float.
//
// R9: ONE kernel, zero workspace. Block = (b, 64-target chunk), 512 threads
// = 8 waves, each wave scans a contiguous N-slice (113/112 preds) against
// the chunk's 64 targets (1 target/lane). Preds staged once in LDS as xyxy
// (wave-uniform ds_read_b128 broadcast, conflict-free). Inner-loop algebra:
//   min(px1,tx1)-max(px0,tx0) == (wp+wt) - ew   (min+max = sum identity)
// so inner w/h come from the enclosing w/h; wp/wpy/pa derived in VALU
// (keeps LDS at ONE b128/iter; a second read would bottleneck the LDS pipe
// at 8 waves/CU-resident-block). ~28 VALU/pair, single v_rcp.
// Completion inline: 64 threads reduce 8 slices ascending (first-occurrence
// ties), margin test, bit-exact winner recompute; ambiguous targets (rare)
// exhaustively rescanned in-block with IEEE math + first-occurrence ties.
// Numerics: approx g err <= ~1e-6 << MARGIN 2e-5 -> argmax provably exact
// outside margin; outputs always computed with bit-exact reference math.

#define BB 128
#define NN 900
#define TT 300
#define TCHUNK 64
#define TBLOCKS 5      // ceil(300/64)
#define NWAVES 8
#define MARGIN 2e-5f

// Bit-exact GIoU in numpy's exact expression order.
__device__ __forceinline__ float giou_exact(float4 pb, float4 tb) {
#pragma clang fp contract(off)
    float px0 = pb.x - 0.5f * pb.z, py0 = pb.y - 0.5f * pb.w;
    float px1 = pb.x + 0.5f * pb.z, py1 = pb.y + 0.5f * pb.w;
    float tx0 = tb.x - 0.5f * tb.z, ty0 = tb.y - 0.5f * tb.w;
    float tx1 = tb.x + 0.5f * tb.z, ty1 = tb.y + 0.5f * tb.w;
    float pa = (px1 - px0) * (py1 - py0);
    float ta = (tx1 - tx0) * (ty1 - ty0);
    float w  = fmaxf(fminf(px1, tx1) - fmaxf(px0, tx0), 0.f);
    float h  = fmaxf(fminf(py1, ty1) - fmaxf(py0, ty0), 0.f);
    float inter = w * h;
    float uni   = pa + ta - inter;
    float iou   = inter / uni;            // correctly-rounded IEEE div
    float ew = fmaxf(fmaxf(px1, tx1) - fminf(px0, tx0), 0.f);
    float eh = fmaxf(fmaxf(py1, ty1) - fminf(py0, ty0), 0.f);
    float ea = ew * eh;
    return iou - (ea - uni) / ea;         // correctly-rounded IEEE div
}

__global__ __launch_bounds__(512) void matcher_kernel(
    const float* __restrict__ pred,          // [B,N,4] cxcywh
    const float* __restrict__ tgt,           // [B,T,4] cxcywh
    const unsigned char* __restrict__ mask,  // [B,T] bool
    float* __restrict__ out)                 // [3, B*T]
{
    __shared__ float4 sp[NN];                // pred xyxy (14.4 KB)
    __shared__ float  rbv[NWAVES * TCHUNK], rsv[NWAVES * TCHUNK];
    __shared__ int    riv[NWAVES * TCHUNK];
    __shared__ int    sflag[TCHUNK];
    __shared__ int    scount;

    const int tc  = blockIdx.x % TBLOCKS;
    const int b   = blockIdx.x / TBLOCKS;
    const int tid = threadIdx.x;
    const int l   = tid & 63;
    const int wv  = tid >> 6;                // wave 0..7
    const int t   = tc * TCHUNK + l;

    if (tid == 0) scount = 0;

    // ---- stage all 900 pred boxes as xyxy into LDS ----
    for (int i = tid; i < NN; i += 512) {
        const float4 pb = ((const float4*)pred)[b * NN + i];
        float4 q;
        q.x = pb.x - 0.5f * pb.z;
        q.y = pb.y - 0.5f * pb.w;
        q.z = pb.x + 0.5f * pb.z;
        q.w = pb.y + 0.5f * pb.w;
        sp[i] = q;
    }

    // ---- per-lane target box ----
    float tx0 = 0.f, ty0 = 0.f, tx1 = 0.f, ty1 = 0.f, ta = 0.f, wtx = 0.f, wty = 0.f;
    if (t < TT) {
        const float4 tb = ((const float4*)tgt)[b * TT + t];
        tx0 = tb.x - 0.5f * tb.z;
        ty0 = tb.y - 0.5f * tb.w;
        tx1 = tb.x + 0.5f * tb.z;
        ty1 = tb.y + 0.5f * tb.w;
        wtx = tx1 - tx0;
        wty = ty1 - ty0;
        ta  = wtx * wty;
    }
    __syncthreads();

    // ---- this wave's contiguous N-slice (ascending across waves) ----
    const int start = wv * 112 + min(wv, 4);        // waves 0-3: 113, 4-7: 112
    const int len   = 112 + (wv < 4 ? 1 : 0);

    float best = -INFINITY, sec = -INFINITY;
    int   bidxl = 0;
    #pragma unroll 4
    for (int k = 0; k < len; ++k) {
        const float4 q = sp[start + k];      // wave-uniform broadcast
        const float wpx = q.z - q.x;
        const float wpy = q.w - q.y;
        const float pa  = wpx * wpy;

        const float ew = fmaxf(q.z, tx1) - fminf(q.x, tx0);   // >= 0
        const float eh = fmaxf(q.w, ty1) - fminf(q.y, ty0);   // >= 0
        const float w  = fmaxf((wpx + wtx) - ew, 0.f);        // = clip(min-max)
        const float h  = fmaxf((wpy + wty) - eh, 0.f);
        const float inter = w * h;
        const float ea    = ew * eh;
        const float uni   = (pa + ta) - inter;
        const float den   = uni * ea;
        // g = inter/uni - (ea-uni)/ea = (inter*ea + uni*(uni-ea))/den
        const float num = fmaf(inter, ea, fmaf(uni, uni, -den));
        const float g   = num * __builtin_amdgcn_rcpf(den);

        sec = __builtin_amdgcn_fmed3f(g, best, sec);
        if (g > best) bidxl = k;
        best = fmaxf(best, g);
    }

    rbv[wv * TCHUNK + l] = best;
    rsv[wv * TCHUNK + l] = sec;
    riv[wv * TCHUNK + l] = start + bidxl;
    __syncthreads();

    // ---- final reduce + margin test + exact winner (threads 0..63) ----
    if (tid < TCHUNK && t < TT) {
        float bb = -INFINITY, ss = -INFINITY;
        int   bi = 0;
        #pragma unroll
        for (int s = 0; s < NWAVES; ++s) {   // ascending wave = ascending n
            const float ob = rbv[s * TCHUNK + tid];
            const float os = rsv[s * TCHUNK + tid];
            const int   oi = riv[s * TCHUNK + tid];
            ss = fmaxf(fminf(bb, ob), fmaxf(ss, os));
            if (ob > bb) { bb = ob; bi = oi; }
        }
        const int bt = b * TT + t;
        if (bb - ss > MARGIN) {
            // approx argmax provably exact; recompute winner bit-exactly
            const float4 pb = ((const float4*)pred)[b * NN + bi];
            const float4 tb = ((const float4*)tgt)[bt];
            const float g = giou_exact(pb, tb);
            const bool valid = (mask[bt] != 0) && (g >= 0.5f);
            out[bt]               = (float)bi;
            out[BB * TT + bt]     = valid ? 1.f : 0.f;
            out[2 * BB * TT + bt] = g;
        } else {
            const int pos = atomicAdd(&scount, 1);
            sflag[pos] = t;
        }
    }
    __syncthreads();

    // ---- exact rescan of ambiguous targets: one wave per entry ----
    const int cnt = scount;
    for (int f = wv; f < cnt; f += NWAVES) {
        const int ft  = sflag[f];
        const int fbt = b * TT + ft;
        const float4 tb = ((const float4*)tgt)[fbt];

        float bx = -INFINITY;
        int   bi = NN;
        for (int n = l; n < NN; n += 64) {       // ascending n per lane
            const float4 pb = ((const float4*)pred)[b * NN + n];
            const float g = giou_exact(pb, tb);
            if (g > bx) { bx = g; bi = n; }
        }
        // cross-lane reduce: max g, lowest n on bit-ties (first occurrence)
        for (int off = 32; off >= 1; off >>= 1) {
            const float ob = __shfl_xor(bx, off);
            const int   oi = __shfl_xor(bi, off);
            if (ob > bx || (ob == bx && oi < bi)) { bx = ob; bi = oi; }
        }
        if (l == 0) {
            const bool valid = (mask[fbt] != 0) && (bx >= 0.5f);
            out[fbt]               = (float)bi;
            out[BB * TT + fbt]     = valid ? 1.f : 0.f;
            out[2 * BB * TT + fbt] = bx;
        }
    }
}

extern "C" void kernel_launch(void* const* d_in, const int* in_sizes, int n_in,
                              void* d_out, int out_size, void* d_ws, size_t ws_size,
                              hipStream_t stream) {
    const float* pred = (const float*)d_in[0];
    const float* tgt  = (const float*)d_in[1];
    const unsigned char* mask = (const unsigned char*)d_in[2];
    float* out = (float*)d_out;

    matcher_kernel<<<dim3(BB * TBLOCKS), dim3(512), 0, stream>>>(
        pred, tgt, mask, out);
}

// Round 10
// 95.602 us; speedup vs baseline: 2.3055x; 1.0001x over previous
//
#include <hip/hip_runtime.h>

// SimpleMatcher: B=128, N=900 preds, T=300 targets.
// out = [pred_idx (B*T), valid (B*T), max_iou (B*T)] as float.
//
// R10: R9's lean inner loop + RESIDENCY fix.
//   R9 (512-thr blocks, grid 640) measured OccupancyPercent 30% -> only
//   ~10 waves/CU; kernel latency-bound at 43.5us vs ~14us issue floor
//   (VALUBusy is gfx94x-formula ~2x inflated on SIMD-32).
//   Now: 256-thr blocks, grid 1280 (b x 5 tchunk x 2 nsplit) -> up to
//   8 blocks/CU = 32 waves/CU. 2-way partials + small finish kernel.
// Inner loop per k (one ds_read_b128): sum-identity
//   min(p1,t1)-max(p0,t0) == (wp+wt)-ew -> inner w/h from enclosing w/h;
//   ~28 VALU + 1 v_rcp per 64 pairs.
// Numerics: approx g = (inter*ea + uni*(uni-ea))*rcp(uni*ea), |err|<=~1e-6
// << MARGIN 2e-5. best-second > MARGIN -> approx argmax provably exact;
// winner recomputed with IEEE ops in numpy's exact order. Ambiguous
// targets exhaustively rescanned exactly (first-occurrence tie-break).

#define BB 128
#define NN 900
#define TT 300
#define TCHUNK 64
#define TBLOCKS 5      // ceil(300/64)
#define NSPLIT 2       // N halves
#define NPB 450        // preds per block
#define MARGIN 2e-5f

// Bit-exact GIoU in numpy's exact expression order.
__device__ __forceinline__ float giou_exact(float4 pb, float4 tb) {
#pragma clang fp contract(off)
    float px0 = pb.x - 0.5f * pb.z, py0 = pb.y - 0.5f * pb.w;
    float px1 = pb.x + 0.5f * pb.z, py1 = pb.y + 0.5f * pb.w;
    float tx0 = tb.x - 0.5f * tb.z, ty0 = tb.y - 0.5f * tb.w;
    float tx1 = tb.x + 0.5f * tb.z, ty1 = tb.y + 0.5f * tb.w;
    float pa = (px1 - px0) * (py1 - py0);
    float ta = (tx1 - tx0) * (ty1 - ty0);
    float w  = fmaxf(fminf(px1, tx1) - fmaxf(px0, tx0), 0.f);
    float h  = fmaxf(fminf(py1, ty1) - fmaxf(py0, ty0), 0.f);
    float inter = w * h;
    float uni   = pa + ta - inter;
    float iou   = inter / uni;            // correctly-rounded IEEE div
    float ew = fmaxf(fmaxf(px1, tx1) - fminf(px0, tx0), 0.f);
    float eh = fmaxf(fmaxf(py1, ty1) - fminf(py0, ty0), 0.f);
    float ea = ew * eh;
    return iou - (ea - uni) / ea;         // correctly-rounded IEEE div
}

__global__ __launch_bounds__(256) void matcher_scan_kernel(
    const float* __restrict__ pred,       // [B,N,4] cxcywh
    const float* __restrict__ tgt,        // [B,T,4] cxcywh
    float* __restrict__ pbest,            // [NSPLIT][B*T]
    float* __restrict__ psec,             // [NSPLIT][B*T]
    int*   __restrict__ pidx)             // [NSPLIT][B*T]
{
    __shared__ float4 sp[NPB];            // pred xyxy (7.2 KB)
    __shared__ float  rbv[4 * TCHUNK], rsv[4 * TCHUNK];
    __shared__ int    riv[4 * TCHUNK];

    const int ns  = blockIdx.x & 1;
    const int tc  = (blockIdx.x >> 1) % TBLOCKS;
    const int b   = blockIdx.x / (NSPLIT * TBLOCKS);
    const int tid = threadIdx.x;
    const int l   = tid & 63;
    const int wv  = tid >> 6;             // wave 0..3
    const int t   = tc * TCHUNK + l;

    // ---- stage this half's 450 pred boxes as xyxy into LDS ----
    for (int i = tid; i < NPB; i += 256) {
        const float4 pb = ((const float4*)pred)[b * NN + ns * NPB + i];
        float4 q;
        q.x = pb.x - 0.5f * pb.z;
        q.y = pb.y - 0.5f * pb.w;
        q.z = pb.x + 0.5f * pb.z;
        q.w = pb.y + 0.5f * pb.w;
        sp[i] = q;
    }

    // ---- per-lane target box ----
    float tx0 = 0.f, ty0 = 0.f, tx1 = 0.f, ty1 = 0.f, ta = 0.f, wtx = 0.f, wty = 0.f;
    if (t < TT) {
        const float4 tb = ((const float4*)tgt)[b * TT + t];
        tx0 = tb.x - 0.5f * tb.z;
        ty0 = tb.y - 0.5f * tb.w;
        tx1 = tb.x + 0.5f * tb.z;
        ty1 = tb.y + 0.5f * tb.w;
        wtx = tx1 - tx0;
        wty = ty1 - ty0;
        ta  = wtx * wty;
    }
    __syncthreads();

    // ---- this wave's slice of the half (ascending across waves) ----
    const int start = wv * 112 + min(wv, 2);       // waves 0-1: 113, 2-3: 112
    const int len   = 112 + (wv < 2 ? 1 : 0);

    float best = -INFINITY, sec = -INFINITY;
    int   bidxl = 0;
    #pragma unroll 4
    for (int k = 0; k < len; ++k) {
        const float4 q = sp[start + k];   // wave-uniform broadcast
        const float wpx = q.z - q.x;
        const float wpy = q.w - q.y;
        const float pa  = wpx * wpy;

        const float ew = fmaxf(q.z, tx1) - fminf(q.x, tx0);   // >= 0
        const float eh = fmaxf(q.w, ty1) - fminf(q.y, ty0);   // >= 0
        const float w  = fmaxf((wpx + wtx) - ew, 0.f);        // = clip(min-max)
        const float h  = fmaxf((wpy + wty) - eh, 0.f);
        const float inter = w * h;
        const float ea    = ew * eh;
        const float uni   = (pa + ta) - inter;
        const float den   = uni * ea;
        // g = inter/uni - (ea-uni)/ea = (inter*ea + uni*(uni-ea))/den
        const float num = fmaf(inter, ea, fmaf(uni, uni, -den));
        const float g   = num * __builtin_amdgcn_rcpf(den);

        sec = __builtin_amdgcn_fmed3f(g, best, sec);
        if (g > best) bidxl = k;
        best = fmaxf(best, g);
    }

    rbv[wv * TCHUNK + l] = best;
    rsv[wv * TCHUNK + l] = sec;
    riv[wv * TCHUNK + l] = start + bidxl;     // index within the half
    __syncthreads();

    // ---- wave 0 reduces 4 slices (ascending wave = ascending n) ----
    if (wv == 0 && t < TT) {
        float bb = best, ss = sec;
        int   bi = start + bidxl;
        #pragma unroll
        for (int s = 1; s < 4; ++s) {
            const float ob = rbv[s * TCHUNK + l];
            const float os = rsv[s * TCHUNK + l];
            const int   oi = riv[s * TCHUNK + l];
            ss = fmaxf(fminf(bb, ob), fmaxf(ss, os));
            if (ob > bb) { bb = ob; bi = oi; }
        }
        const int bt = b * TT + t;
        pbest[ns * BB * TT + bt] = bb;
        psec [ns * BB * TT + bt] = ss;
        pidx [ns * BB * TT + bt] = ns * NPB + bi;   // global pred index
    }
}

__global__ __launch_bounds__(256) void matcher_finish_kernel(
    const float* __restrict__ pbest,
    const float* __restrict__ psec,
    const int*   __restrict__ pidx,
    const float* __restrict__ pred,
    const float* __restrict__ tgt,
    const unsigned char* __restrict__ mask,
    float* __restrict__ out)
{
    __shared__ int sflag[256];
    __shared__ int scount;

    const int tid = threadIdx.x;
    const int bt  = blockIdx.x * 256 + tid;   // grid covers exactly B*T
    if (tid == 0) scount = 0;
    __syncthreads();

    float best = -INFINITY, second = -INFINITY;
    int   bidx = 0;
    #pragma unroll
    for (int s = 0; s < NSPLIT; ++s) {        // ascending ns = ascending n
        const float ob = pbest[s * BB * TT + bt];
        const float os = psec [s * BB * TT + bt];
        const int   oi = pidx [s * BB * TT + bt];
        second = fmaxf(fminf(best, ob), fmaxf(second, os));
        if (ob > best) { best = ob; bidx = oi; }
    }

    if (best - second > MARGIN) {
        // approx argmax provably exact; recompute winner's GIoU bit-exactly
        const int b = bt / TT;
        const float4 pb = ((const float4*)pred)[b * NN + bidx];
        const float4 tb = ((const float4*)tgt)[bt];
        const float g = giou_exact(pb, tb);
        const bool valid = (mask[bt] != 0) && (g >= 0.5f);
        out[bt]               = (float)bidx;
        out[BB * TT + bt]     = valid ? 1.f : 0.f;
        out[2 * BB * TT + bt] = g;
    } else {
        const int pos = atomicAdd(&scount, 1);
        sflag[pos] = tid;
    }
    __syncthreads();

    // cooperative exact rescan of ambiguous targets: one wave per entry
    const int cnt  = scount;
    const int lane = tid & 63;
    const int wv   = tid >> 6;
    for (int f = wv; f < cnt; f += 4) {
        const int fbt = blockIdx.x * 256 + sflag[f];
        const int b   = fbt / TT;
        const float4 tb = ((const float4*)tgt)[fbt];

        float bx = -INFINITY;
        int   bi = NN;
        for (int n = lane; n < NN; n += 64) {   // ascending n per lane
            const float4 pb = ((const float4*)pred)[b * NN + n];
            const float g = giou_exact(pb, tb);
            if (g > bx) { bx = g; bi = n; }
        }
        // cross-lane reduce: max g, lowest n on bit-ties (first occurrence)
        for (int off = 32; off >= 1; off >>= 1) {
            const float ob = __shfl_xor(bx, off);
            const int   oi = __shfl_xor(bi, off);
            if (ob > bx || (ob == bx && oi < bi)) { bx = ob; bi = oi; }
        }
        if (lane == 0) {
            const bool valid = (mask[fbt] != 0) && (bx >= 0.5f);
            out[fbt]               = (float)bi;
            out[BB * TT + fbt]     = valid ? 1.f : 0.f;
            out[2 * BB * TT + fbt] = bx;
        }
    }
}

extern "C" void kernel_launch(void* const* d_in, const int* in_sizes, int n_in,
                              void* d_out, int out_size, void* d_ws, size_t ws_size,
                              hipStream_t stream) {
    const float* pred = (const float*)d_in[0];
    const float* tgt  = (const float*)d_in[1];
    const unsigned char* mask = (const unsigned char*)d_in[2];
    float* out = (float*)d_out;

    const size_t seg = (size_t)NSPLIT * BB * TT * 4;   // 307 KB per array
    char* ws = (char*)d_ws;
    float* pbest = (float*)ws;
    float* psec  = (float*)(ws + seg);
    int*   pidx  = (int*)  (ws + 2 * seg);             // total ~0.92 MB

    matcher_scan_kernel<<<dim3(BB * TBLOCKS * NSPLIT), dim3(256), 0, stream>>>(
        pred, tgt, pbest, psec, pidx);
    matcher_finish_kernel<<<dim3(BB * TT / 256), dim3(256), 0, stream>>>(
        pbest, psec, pidx, pred, tgt, mask, out);
}